// Round 7
// baseline (183.608 us; speedup 1.0000x reference)
//
#include <hip/hip_runtime.h>
#include <hip/hip_bf16.h>

typedef __bf16 bf16x8 __attribute__((ext_vector_type(8)));
typedef float f32x4 __attribute__((ext_vector_type(4)));
typedef float f32x8 __attribute__((ext_vector_type(8)));
typedef unsigned short u16x8 __attribute__((ext_vector_type(8)));

#define MFMA16(a, b, c) __builtin_amdgcn_mfma_f32_16x16x32_bf16((a), (b), (c), 0, 0, 0)

static __device__ __forceinline__ unsigned short f2b(float f) {
    union { float f; unsigned int u; } v; v.f = f;
    unsigned int r = v.u + 0x7FFFu + ((v.u >> 16) & 1u);  // RNE
    return (unsigned short)(r >> 16);
}
static __device__ __forceinline__ float b2f(unsigned short s) {
    union { unsigned int u; float f; } v; v.u = ((unsigned int)s) << 16;
    return v.f;
}
static __device__ __forceinline__ bf16x8 cvtv(f32x8 v) {
    bf16x8 r;
    #pragma unroll
    for (int i = 0; i < 8; ++i) r[i] = (__bf16)v[i];
    return r;
}

// ---------------- precompute: Mt = (Wq^T Wk)^T, N = Wl*Wv  (bf16, in d_ws) ----
__global__ __launch_bounds__(256) void precompute_mn(
    const float* __restrict__ Wq, const float* __restrict__ Wk,
    const float* __restrict__ Wv, const float* __restrict__ Wl,
    unsigned short* __restrict__ ws)
{
    __shared__ float A[4096], B[4096];
    const int bid = blockIdx.x;          // 8 blocks
    const int which = bid >> 2;          // 0 = Mt, 1 = N
    const int rq = bid & 3;              // row quad
    const int tid = threadIdx.x;
    for (int i = tid; i < 4096; i += 256) {
        A[i] = which ? Wl[i] : Wq[i];
        B[i] = which ? Wv[i] : Wk[i];
    }
    __syncthreads();
    const int row = rq * 16 + (tid >> 4);
    const int c0  = tid & 15;
    float acc[4] = {0, 0, 0, 0};
    if (which == 0) {        // Mt[row][col] = sum_e Wq[e][col] * Wk[e][row]
        for (int e = 0; e < 64; ++e) {
            const float s = B[e * 64 + row];
            #pragma unroll
            for (int i = 0; i < 4; ++i) acc[i] += A[e * 64 + c0 + 16 * i] * s;
        }
    } else {                 // N[row][col] = sum_c Wl[row][c] * Wv[c][col]
        for (int c = 0; c < 64; ++c) {
            const float s = A[row * 64 + c];
            #pragma unroll
            for (int i = 0; i < 4; ++i) acc[i] += s * B[c * 64 + c0 + 16 * i];
        }
    }
    #pragma unroll
    for (int i = 0; i < 4; ++i)
        ws[which * 4096 + row * 64 + c0 + 16 * i] = f2b(acc[i]);
}

#define PITCH 68
#define NTASK 6

// Persistent-ish pipelined kernel: 1024 blocks x 256 threads (4 waves), each
// block runs NTASK=6 consecutive tasks (6 heads of one window). Task i+1's
// gather loads are issued at the top of task i's compute; staging for i+1
// lands in the barrier slot after U(i); F(i)/out(i) overlap the staging.
// Chain per task: T = qw*Mt^T -> S = T*kw^T (/8+bias+mask, softmax) ->
// U = P*vw -> F = U*N^T.  mfma 16x16x32 bf16: a/b-frag lane l holds row/col
// (l&15), k=(l>>4)*8+i; D: col = lane&15, row = (lane>>4)*4 + reg.
__global__ __launch_bounds__(256, 4) void swca_fused(
    const float* __restrict__ qf,
    const float* __restrict__ kf,
    const float* __restrict__ vf,
    const unsigned short* __restrict__ Mt,   // ws
    const unsigned short* __restrict__ Nw,   // ws + 4096
    const float* __restrict__ pe,
    float* __restrict__ out,
    float* __restrict__ attn)
{
    __shared__ unsigned short kwS[64][PITCH];  // raw K features (bf16)
    __shared__ unsigned short vwT[64][PITCH];  // raw V features, transposed
    __shared__ unsigned short As[64][PITCH];   // T -> P -> U (wave-private bands)

    const int tid  = threadIdx.x;
    const int wid  = tid >> 6;
    const int lane = tid & 63;
    const int lg   = lane >> 4;   // k-group 0..3
    const int lc   = lane & 15;   // row/col within 16-tile
    const int srow = wid * 16 + lc;
    const int sy = srow >> 3, sx = srow & 7;
    const int r0 = wid * 16 + lg * 4;

    auto ld8 = [](const unsigned short* p) -> bf16x8 {
        return *reinterpret_cast<const bf16x8*>(p);
    };

    int task = blockIdx.x * NTASK;

    // decode current task
    int headC = task % 12; { }
    int t2 = task / 12;
    int winC = t2 & 63, bC = t2 >> 6;
    long rbC;
    {
        const int wy = winC >> 3, wx = winC & 7;
        const int gy = (wy * 8 + sy + 4) & 63;
        const int gx = (wx * 8 + sx + 4) & 63;
        rbC = ((long)bC * 4096 + gy * 64 + gx) * 768 + headC * 64;
    }
    // prologue loads + staging for task 0
    f32x8 cq0 = *reinterpret_cast<const f32x8*>(qf + rbC + lg * 8);
    f32x8 cq1 = *reinterpret_cast<const f32x8*>(qf + rbC + 32 + lg * 8);
    f32x8 ck0 = *reinterpret_cast<const f32x8*>(kf + rbC + lg * 8);
    f32x8 ck1 = *reinterpret_cast<const f32x8*>(kf + rbC + 32 + lg * 8);
    f32x8 cv0 = *reinterpret_cast<const f32x8*>(vf + rbC + lg * 8);
    f32x8 cv1 = *reinterpret_cast<const f32x8*>(vf + rbC + 32 + lg * 8);

    *reinterpret_cast<bf16x8*>(&kwS[srow][lg * 8]) = cvtv(ck0);
    *reinterpret_cast<bf16x8*>(&kwS[srow][32 + lg * 8]) = cvtv(ck1);
    #pragma unroll
    for (int i = 0; i < 8; ++i) {
        vwT[lg * 8 + i][srow] = f2b(cv0[i]);
        vwT[32 + lg * 8 + i][srow] = f2b(cv1[i]);
    }
    __syncthreads();

    for (int it = 0; it < NTASK; ++it) {
        // ---- prefetch next task (loads in flight through this task's compute)
        f32x8 nq0 = {}, nq1 = {}, nk0 = {}, nk1 = {}, nv0 = {}, nv1 = {};
        int headN = 0, winN = 0, bN = 0;
        long rbN = 0;
        if (it + 1 < NTASK) {
            const int taskN = task + 1;
            headN = taskN % 12;
            const int t2n = taskN / 12;
            winN = t2n & 63; bN = t2n >> 6;
            const int wy = winN >> 3, wx = winN & 7;
            const int gy = (wy * 8 + sy + 4) & 63;
            const int gx = (wx * 8 + sx + 4) & 63;
            rbN = ((long)bN * 4096 + gy * 64 + gx) * 768 + headN * 64;
            nq0 = *reinterpret_cast<const f32x8*>(qf + rbN + lg * 8);
            nq1 = *reinterpret_cast<const f32x8*>(qf + rbN + 32 + lg * 8);
            nk0 = *reinterpret_cast<const f32x8*>(kf + rbN + lg * 8);
            nk1 = *reinterpret_cast<const f32x8*>(kf + rbN + 32 + lg * 8);
            nv0 = *reinterpret_cast<const f32x8*>(vf + rbN + lg * 8);
            nv1 = *reinterpret_cast<const f32x8*>(vf + rbN + 32 + lg * 8);
        }
        const int wy = winC >> 3, wx = winC & 7;

        // ---- T = qw * Mt^T (wave-private band of As)
        {
            bf16x8 qa0 = cvtv(cq0), qa1 = cvtv(cq1);
            f32x4 acc[4] = {};
            #pragma unroll
            for (int t = 0; t < 4; ++t) {
                acc[t] = MFMA16(qa0, ld8(Mt + (t * 16 + lc) * 64 + lg * 8), acc[t]);
                acc[t] = MFMA16(qa1, ld8(Mt + (t * 16 + lc) * 64 + 32 + lg * 8), acc[t]);
            }
            #pragma unroll
            for (int t = 0; t < 4; ++t)
                #pragma unroll
                for (int j = 0; j < 4; ++j)
                    As[wid * 16 + lg * 4 + j][t * 16 + lc] = f2b(acc[t][j]);
        }

        // ---- S = T * kw^T (/8 + bias + mask), softmax -> P (bf16 in As)
        f32x4 accS[4] = {};
        {
            bf16x8 a0 = ld8(&As[srow][lg * 8]);
            bf16x8 a1 = ld8(&As[srow][32 + lg * 8]);
            #pragma unroll
            for (int t = 0; t < 4; ++t) {
                accS[t] = MFMA16(a0, ld8(&kwS[t * 16 + lc][lg * 8]), accS[t]);
                accS[t] = MFMA16(a1, ld8(&kwS[t * 16 + lc][32 + lg * 8]), accS[t]);
            }
        }
        {
            float sv[4][4];
            #pragma unroll
            for (int t = 0; t < 4; ++t) {
                const int c = t * 16 + lc, ky = c >> 3, kx = c & 7;
                #pragma unroll
                for (int j = 0; j < 4; ++j) {
                    const int r = r0 + j, qy = r >> 3, qx = r & 7;
                    const float biasv = pe[(ky - qy + 7) * 15 + (kx - qx + 7)];
                    const bool msk = ((wy == 7) && (((qy ^ ky) & 4) != 0)) ||
                                     ((wx == 7) && (((qx ^ kx) & 4) != 0));
                    sv[t][j] = msk ? -__builtin_inff() : accS[t][j] * 0.125f + biasv;
                }
            }
            #pragma unroll
            for (int j = 0; j < 4; ++j) {
                float mx = fmaxf(fmaxf(sv[0][j], sv[1][j]), fmaxf(sv[2][j], sv[3][j]));
                mx = fmaxf(mx, __shfl_xor(mx, 1));
                mx = fmaxf(mx, __shfl_xor(mx, 2));
                mx = fmaxf(mx, __shfl_xor(mx, 4));
                mx = fmaxf(mx, __shfl_xor(mx, 8));
                const float e0 = __expf(sv[0][j] - mx);
                const float e1 = __expf(sv[1][j] - mx);
                const float e2 = __expf(sv[2][j] - mx);
                const float e3 = __expf(sv[3][j] - mx);
                float sm = (e0 + e1) + (e2 + e3);
                sm += __shfl_xor(sm, 1);
                sm += __shfl_xor(sm, 2);
                sm += __shfl_xor(sm, 4);
                sm += __shfl_xor(sm, 8);
                const float inv = 1.0f / sm;
                As[r0 + j][0 * 16 + lc] = f2b(e0 * inv);
                As[r0 + j][1 * 16 + lc] = f2b(e1 * inv);
                As[r0 + j][2 * 16 + lc] = f2b(e2 * inv);
                As[r0 + j][3 * 16 + lc] = f2b(e3 * inv);
            }
        }

        // ---- read P frags, dump attn (wave-local, full 64B lines), U = P*vw
        {
            bf16x8 a0 = ld8(&As[srow][lg * 8]);
            bf16x8 a1 = ld8(&As[srow][32 + lg * 8]);

            {   // attn dump: lane covers row wid*16+(lane>>2), 16 cols
                const int lr = wid * 16 + (lane >> 2);
                const int c0 = (lane & 3) * 16;
                u16x8 p0 = *reinterpret_cast<const u16x8*>(&As[lr][c0]);
                u16x8 p1 = *reinterpret_cast<const u16x8*>(&As[lr][c0 + 8]);
                const long abase = ((((long)bC * 12 + headC) * 64 + winC) * 64 + lr) * 64 + c0;
                f32x4 o0, o1, o2, o3;
                #pragma unroll
                for (int i = 0; i < 4; ++i) { o0[i] = b2f(p0[i]); o1[i] = b2f(p0[4 + i]); }
                #pragma unroll
                for (int i = 0; i < 4; ++i) { o2[i] = b2f(p1[i]); o3[i] = b2f(p1[4 + i]); }
                *reinterpret_cast<f32x4*>(attn + abase)      = o0;
                *reinterpret_cast<f32x4*>(attn + abase + 4)  = o1;
                *reinterpret_cast<f32x4*>(attn + abase + 8)  = o2;
                *reinterpret_cast<f32x4*>(attn + abase + 12) = o3;
            }

            f32x4 acc[4] = {};
            #pragma unroll
            for (int t = 0; t < 4; ++t) {
                acc[t] = MFMA16(a0, ld8(&vwT[t * 16 + lc][lg * 8]), acc[t]);
                acc[t] = MFMA16(a1, ld8(&vwT[t * 16 + lc][32 + lg * 8]), acc[t]);
            }
            #pragma unroll
            for (int t = 0; t < 4; ++t)
                #pragma unroll
                for (int j = 0; j < 4; ++j)
                    As[wid * 16 + lg * 4 + j][t * 16 + lc] = f2b(acc[t][j]);
        }

        __syncthreads();   // all waves done with kwS/vwT of task it

        // ---- stage next task's kw/vw (overlaps F/out below)
        if (it + 1 < NTASK) {
            *reinterpret_cast<bf16x8*>(&kwS[srow][lg * 8]) = cvtv(nk0);
            *reinterpret_cast<bf16x8*>(&kwS[srow][32 + lg * 8]) = cvtv(nk1);
            #pragma unroll
            for (int i = 0; i < 8; ++i) {
                vwT[lg * 8 + i][srow] = f2b(nv0[i]);
                vwT[32 + lg * 8 + i][srow] = f2b(nv1[i]);
            }
        }

        // ---- F = U * N^T, direct fp32 scatter (reads As only)
        {
            bf16x8 a0 = ld8(&As[srow][lg * 8]);
            bf16x8 a1 = ld8(&As[srow][32 + lg * 8]);
            f32x4 acc[4] = {};
            #pragma unroll
            for (int t = 0; t < 4; ++t) {
                acc[t] = MFMA16(a0, ld8(Nw + (t * 16 + lc) * 64 + lg * 8), acc[t]);
                acc[t] = MFMA16(a1, ld8(Nw + (t * 16 + lc) * 64 + 32 + lg * 8), acc[t]);
            }
            #pragma unroll
            for (int j = 0; j < 4; ++j) {
                const int r = r0 + j, ry = r >> 3, rx = r & 7;
                const int oy = (wy * 8 + ry + 4) & 63;
                const int ox = (wx * 8 + rx + 4) & 63;
                const long obase = ((long)bC * 4096 + oy * 64 + ox) * 768 + headC * 64;
                #pragma unroll
                for (int t = 0; t < 4; ++t)
                    out[obase + t * 16 + lc] = acc[t][j];
            }
        }

        __syncthreads();   // staging complete before next iter reads kwS/vwT

        // ---- rotate pipeline state
        cq0 = nq0; cq1 = nq1;
        headC = headN; winC = winN; bC = bN;
        task = task + 1;
    }
}

extern "C" void kernel_launch(void* const* d_in, const int* in_sizes, int n_in,
                              void* d_out, int out_size, void* d_ws, size_t ws_size,
                              hipStream_t stream) {
    const float* qf = (const float*)d_in[0];
    const float* kf = (const float*)d_in[1];
    const float* vf = (const float*)d_in[2];
    const float* Wq = (const float*)d_in[3];
    const float* Wk = (const float*)d_in[4];
    const float* Wv = (const float*)d_in[5];
    const float* Wl = (const float*)d_in[6];
    const float* pe = (const float*)d_in[7];

    const int B = in_sizes[0] / (4096 * 768);   // 8
    float* outp = (float*)d_out;
    float* attnp = outp + (size_t)B * 4096 * 768;
    unsigned short* ws = (unsigned short*)d_ws;

    precompute_mn<<<8, 256, 0, stream>>>(Wq, Wk, Wv, Wl, ws);

    const int nblk = B * 768 / NTASK;   // 1024 persistent-ish blocks
    swca_fused<<<nblk, 256, 0, stream>>>(qf, kf, vf, ws, ws + 4096, pe,
                                         outp, attnp);
}

// Round 8
// 142.563 us; speedup vs baseline: 1.2879x; 1.2879x over previous
//
#include <hip/hip_runtime.h>
#include <hip/hip_bf16.h>

typedef __bf16 bf16x8 __attribute__((ext_vector_type(8)));
typedef float f32x4 __attribute__((ext_vector_type(4)));
typedef float f32x8 __attribute__((ext_vector_type(8)));
typedef unsigned short u16x8 __attribute__((ext_vector_type(8)));

#define MFMA16(a, b, c) __builtin_amdgcn_mfma_f32_16x16x32_bf16((a), (b), (c), 0, 0, 0)

static __device__ __forceinline__ unsigned short f2b(float f) {
    union { float f; unsigned int u; } v; v.f = f;
    unsigned int r = v.u + 0x7FFFu + ((v.u >> 16) & 1u);  // RNE
    return (unsigned short)(r >> 16);
}
static __device__ __forceinline__ float b2f(unsigned short s) {
    union { unsigned int u; float f; } v; v.u = ((unsigned int)s) << 16;
    return v.f;
}
static __device__ __forceinline__ bf16x8 cvtv(f32x8 v) {
    bf16x8 r;
    #pragma unroll
    for (int i = 0; i < 8; ++i) r[i] = (__bf16)v[i];
    return r;
}

// ---------------- precompute (bf16, in d_ws) ----------------
// M[d][dp] = sum_e Wq[e][d] * Wk[e][dp]   (B-operand for KM = kw * M^T)
// N[e][d]  = sum_c Wl[e][c] * Wv[c][d]    (B-operand for VN = vw * N^T)
__global__ __launch_bounds__(256) void precompute_mn(
    const float* __restrict__ Wq, const float* __restrict__ Wk,
    const float* __restrict__ Wv, const float* __restrict__ Wl,
    unsigned short* __restrict__ ws)
{
    __shared__ float A[4096], B[4096];
    const int bid = blockIdx.x;          // 8 blocks
    const int which = bid >> 2;          // 0 = M, 1 = N
    const int rq = bid & 3;              // row quad
    const int tid = threadIdx.x;
    for (int i = tid; i < 4096; i += 256) {
        A[i] = which ? Wl[i] : Wq[i];
        B[i] = which ? Wv[i] : Wk[i];
    }
    __syncthreads();
    const int row = rq * 16 + (tid >> 4);
    const int c0  = tid & 15;
    float acc[4] = {0, 0, 0, 0};
    if (which == 0) {        // M[row][col] = sum_e Wq[e][row] * Wk[e][col]
        for (int e = 0; e < 64; ++e) {
            const float s = A[e * 64 + row];
            #pragma unroll
            for (int i = 0; i < 4; ++i) acc[i] += s * B[e * 64 + c0 + 16 * i];
        }
    } else {                 // N[row][col] = sum_c Wl[row][c] * Wv[c][col]
        for (int c = 0; c < 64; ++c) {
            const float s = A[row * 64 + c];
            #pragma unroll
            for (int i = 0; i < 4; ++i) acc[i] += s * B[c * 64 + c0 + 16 * i];
        }
    }
    #pragma unroll
    for (int i = 0; i < 4; ++i)
        ws[which * 4096 + row * 64 + c0 + 16 * i] = f2b(acc[i]);
}

#define PITCH 68

// One block = TWO (b, head, window) tasks, 512 threads = 8 waves, 4/task.
// Pre-barrier (per wave): KM = kw*M^T -> kmS, VN = vw*N^T -> vnT[e][k].
// Post-barrier: S = qw*KM^T (raw q regs as A!) -> softmax -> P -> F = P*VN^T.
// Only ONE barrier; As (P) is wave-private. mfma 16x16x32 bf16: a/b-frag
// lane l holds row/col (l&15), k=(l>>4)*8+i; D: col=lane&15, row=(lane>>4)*4+reg.
__global__ __launch_bounds__(512) void swca_fused(
    const float* __restrict__ qf,
    const float* __restrict__ kf,
    const float* __restrict__ vf,
    const unsigned short* __restrict__ Mw,   // ws
    const unsigned short* __restrict__ Nw,   // ws + 4096
    const float* __restrict__ pe,
    float* __restrict__ out,
    float* __restrict__ attn,
    int nblk2)
{
    __shared__ unsigned short kmS[2][64][PITCH];  // KM = kw*M^T  [k][d]
    __shared__ unsigned short vnT[2][64][PITCH];  // VN^T         [e][k]
    __shared__ unsigned short As[2][64][PITCH];   // P (wave-private bands)

    int bid = blockIdx.x;
    const int nper = nblk2 >> 3;                 // XCD-chunked swizzle
    const int task2 = (bid & 7) * nper + (bid >> 3);

    const int tid = threadIdx.x;
    const int h2  = tid >> 8;                    // which task half
    int task = task2 * 2 + h2;

    const int head = task % 12; task /= 12;
    const int win  = task & 63;
    const int b    = task >> 6;
    const int wy = win >> 3, wx = win & 7;

    const int tt   = tid & 255;
    const int wid  = tt >> 6;
    const int lane = tt & 63;
    const int lg   = lane >> 4;   // k-group 0..3
    const int lc   = lane & 15;   // row/col within 16-tile
    const int srow = wid * 16 + lc;

    // shifted-window gather: window row s -> global (y,x) with +4 roll
    const int sy = srow >> 3, sx = srow & 7;
    const int gy = (wy * 8 + sy + 4) & 63;
    const int gx = (wx * 8 + sx + 4) & 63;
    const long rowbase = ((long)b * 4096 + gy * 64 + gx) * 768 + head * 64;

    auto ld8 = [](const unsigned short* p) -> bf16x8 {
        return *reinterpret_cast<const bf16x8*>(p);
    };

    // ---------------- loads (k/v gate the barrier; q only gates S) --------
    bf16x8 kb0 = cvtv(*reinterpret_cast<const f32x8*>(kf + rowbase + lg * 8));
    bf16x8 kb1 = cvtv(*reinterpret_cast<const f32x8*>(kf + rowbase + 32 + lg * 8));
    bf16x8 vb0 = cvtv(*reinterpret_cast<const f32x8*>(vf + rowbase + lg * 8));
    bf16x8 vb1 = cvtv(*reinterpret_cast<const f32x8*>(vf + rowbase + 32 + lg * 8));
    bf16x8 qa0 = cvtv(*reinterpret_cast<const f32x8*>(qf + rowbase + lg * 8));
    bf16x8 qa1 = cvtv(*reinterpret_cast<const f32x8*>(qf + rowbase + 32 + lg * 8));

    // ---------------- pre-barrier: KM and VN ----------------
    { // KM = kw * M^T  (rows = this wave's kw rows)
        f32x4 acc[4] = {};
        #pragma unroll
        for (int t = 0; t < 4; ++t) {
            acc[t] = MFMA16(kb0, ld8(Mw + (t * 16 + lc) * 64 + lg * 8), acc[t]);
            acc[t] = MFMA16(kb1, ld8(Mw + (t * 16 + lc) * 64 + 32 + lg * 8), acc[t]);
        }
        #pragma unroll
        for (int t = 0; t < 4; ++t)
            #pragma unroll
            for (int j = 0; j < 4; ++j)
                kmS[h2][wid * 16 + lg * 4 + j][t * 16 + lc] = f2b(acc[t][j]);
    }
    { // VN = vw * N^T, stored transposed: vnT[e][k]
        f32x4 acc[4] = {};
        #pragma unroll
        for (int t = 0; t < 4; ++t) {
            acc[t] = MFMA16(vb0, ld8(Nw + (t * 16 + lc) * 64 + lg * 8), acc[t]);
            acc[t] = MFMA16(vb1, ld8(Nw + (t * 16 + lc) * 64 + 32 + lg * 8), acc[t]);
        }
        #pragma unroll
        for (int t = 0; t < 4; ++t)
            #pragma unroll
            for (int j = 0; j < 4; ++j)
                vnT[h2][t * 16 + lc][wid * 16 + lg * 4 + j] = f2b(acc[t][j]);
    }
    __syncthreads();   // the ONLY barrier

    // ---------------- S = qw * KM^T (/8 + bias + mask), softmax ------------
    f32x4 accS[4] = {};
    {
        #pragma unroll
        for (int t = 0; t < 4; ++t) {
            accS[t] = MFMA16(qa0, ld8(&kmS[h2][t * 16 + lc][lg * 8]), accS[t]);
            accS[t] = MFMA16(qa1, ld8(&kmS[h2][t * 16 + lc][32 + lg * 8]), accS[t]);
        }
    }
    const int r0 = wid * 16 + lg * 4;
    {
        float sv[4][4];
        #pragma unroll
        for (int t = 0; t < 4; ++t) {
            const int c = t * 16 + lc, ky = c >> 3, kx = c & 7;
            #pragma unroll
            for (int j = 0; j < 4; ++j) {
                const int r = r0 + j, qy = r >> 3, qx = r & 7;
                const float biasv = pe[(ky - qy + 7) * 15 + (kx - qx + 7)];
                const bool msk = ((wy == 7) && (((qy ^ ky) & 4) != 0)) ||
                                 ((wx == 7) && (((qx ^ kx) & 4) != 0));
                sv[t][j] = msk ? -__builtin_inff() : accS[t][j] * 0.125f + biasv;
            }
        }
        #pragma unroll
        for (int j = 0; j < 4; ++j) {
            float mx = fmaxf(fmaxf(sv[0][j], sv[1][j]), fmaxf(sv[2][j], sv[3][j]));
            mx = fmaxf(mx, __shfl_xor(mx, 1));
            mx = fmaxf(mx, __shfl_xor(mx, 2));
            mx = fmaxf(mx, __shfl_xor(mx, 4));
            mx = fmaxf(mx, __shfl_xor(mx, 8));   // row lives in one 16-lane group
            const float e0 = __expf(sv[0][j] - mx);
            const float e1 = __expf(sv[1][j] - mx);
            const float e2 = __expf(sv[2][j] - mx);
            const float e3 = __expf(sv[3][j] - mx);
            float sm = (e0 + e1) + (e2 + e3);
            sm += __shfl_xor(sm, 1);
            sm += __shfl_xor(sm, 2);
            sm += __shfl_xor(sm, 4);
            sm += __shfl_xor(sm, 8);
            const float inv = 1.0f / sm;
            As[h2][r0 + j][0 * 16 + lc] = f2b(e0 * inv);
            As[h2][r0 + j][1 * 16 + lc] = f2b(e1 * inv);
            As[h2][r0 + j][2 * 16 + lc] = f2b(e2 * inv);
            As[h2][r0 + j][3 * 16 + lc] = f2b(e3 * inv);
        }
    }

    // ---------------- attn dump (wave-local, full 64B lines) ---------------
    {
        const int lr = wid * 16 + (lane >> 2);
        const int c0 = (lane & 3) * 16;
        u16x8 p0 = *reinterpret_cast<const u16x8*>(&As[h2][lr][c0]);
        u16x8 p1 = *reinterpret_cast<const u16x8*>(&As[h2][lr][c0 + 8]);
        const long abase = ((((long)b * 12 + head) * 64 + win) * 64 + lr) * 64 + c0;
        f32x4 o0, o1, o2, o3;
        #pragma unroll
        for (int i = 0; i < 4; ++i) { o0[i] = b2f(p0[i]); o1[i] = b2f(p0[4 + i]); }
        #pragma unroll
        for (int i = 0; i < 4; ++i) { o2[i] = b2f(p1[i]); o3[i] = b2f(p1[4 + i]); }
        *reinterpret_cast<f32x4*>(attn + abase)      = o0;
        *reinterpret_cast<f32x4*>(attn + abase + 4)  = o1;
        *reinterpret_cast<f32x4*>(attn + abase + 8)  = o2;
        *reinterpret_cast<f32x4*>(attn + abase + 12) = o3;
    }

    // ---------------- F = P * VN^T, direct fp32 scatter ---------------------
    {
        bf16x8 a0 = ld8(&As[h2][srow][lg * 8]);
        bf16x8 a1 = ld8(&As[h2][srow][32 + lg * 8]);
        f32x4 acc[4] = {};
        #pragma unroll
        for (int t = 0; t < 4; ++t) {
            acc[t] = MFMA16(a0, ld8(&vnT[h2][t * 16 + lc][lg * 8]), acc[t]);
            acc[t] = MFMA16(a1, ld8(&vnT[h2][t * 16 + lc][32 + lg * 8]), acc[t]);
        }
        #pragma unroll
        for (int j = 0; j < 4; ++j) {
            const int r = r0 + j, ry = r >> 3, rx = r & 7;
            const int oy = (wy * 8 + ry + 4) & 63;
            const int ox = (wx * 8 + rx + 4) & 63;
            const long obase = ((long)b * 4096 + oy * 64 + ox) * 768 + head * 64;
            #pragma unroll
            for (int t = 0; t < 4; ++t)
                out[obase + t * 16 + lc] = acc[t][j];
        }
    }
}

extern "C" void kernel_launch(void* const* d_in, const int* in_sizes, int n_in,
                              void* d_out, int out_size, void* d_ws, size_t ws_size,
                              hipStream_t stream) {
    const float* qf = (const float*)d_in[0];
    const float* kf = (const float*)d_in[1];
    const float* vf = (const float*)d_in[2];
    const float* Wq = (const float*)d_in[3];
    const float* Wk = (const float*)d_in[4];
    const float* Wv = (const float*)d_in[5];
    const float* Wl = (const float*)d_in[6];
    const float* pe = (const float*)d_in[7];

    const int B = in_sizes[0] / (4096 * 768);   // 8
    float* outp = (float*)d_out;
    float* attnp = outp + (size_t)B * 4096 * 768;
    unsigned short* ws = (unsigned short*)d_ws;

    precompute_mn<<<8, 256, 0, stream>>>(Wq, Wk, Wv, Wl, ws);

    const int nblk2 = B * 768 / 2;   // 2 tasks per block
    swca_fused<<<nblk2, 512, 0, stream>>>(qf, kf, vf, ws, ws + 4096, pe,
                                          outp, attnp, nblk2);
}